// Round 2
// baseline (10780.602 us; speedup 1.0000x reference)
//
#include <hip/hip_runtime.h>
#include <hip/hip_bf16.h>
#include <stdint.h>

#define T_STEPS 512
#define BATCH   256
#define HID     256

#define NRWG   64      // recurrence workgroups (4 batch rows each)
#define NWWG   192     // xgemm worker workgroups
#define NWG    256
#define RING   4       // Zx ring slots
#define CHUNK  16      // time steps per chunk
#define NCHUNK 32
#define TPC    256     // tiles per chunk: (16*256/128) * (1024/128)
#define SLOT_F (CHUNK*256*1024)   // floats per ring slot

using short8 = __attribute__((ext_vector_type(8))) short;
using f32x4  = __attribute__((ext_vector_type(4))) float;

__device__ inline unsigned short f2bf(float f) {
  unsigned u = __float_as_uint(f);
  unsigned r = (u + 0x7fffu + ((u >> 16) & 1u)) >> 16;
  return (unsigned short)r;
}
__device__ inline float sigm(float x)   { return __builtin_amdgcn_rcpf(1.0f + __expf(-x)); }
__device__ inline float tanh_f(float x) { return 2.0f * __builtin_amdgcn_rcpf(1.0f + __expf(-2.0f * x)) - 1.0f; }

__device__ inline int ld_acq(const int* p) {
  return __hip_atomic_load(p, __ATOMIC_ACQUIRE, __HIP_MEMORY_SCOPE_AGENT);
}
__device__ inline void add_rel(int* p, int v) {
  __hip_atomic_fetch_add(p, v, __ATOMIC_RELEASE, __HIP_MEMORY_SCOPE_AGENT);
}
__device__ inline float ldg_coh(const float* p) {
  return __hip_atomic_load(p, __ATOMIC_RELAXED, __HIP_MEMORY_SCOPE_AGENT);
}
__device__ inline void stg_coh(float* p, float v) {
  __hip_atomic_store(p, v, __ATOMIC_RELAXED, __HIP_MEMORY_SCOPE_AGENT);
}

// ---------------- prep: pack weights + zero flags ----------------
// Wfull : [1024 cols][768 k] bf16 ; cvec : [1024] = bias + theta
__global__ __launch_bounds__(256) void prep_kernel(
    const float* __restrict__ Wf, const float* __restrict__ Wi,
    const float* __restrict__ Wg, const float* __restrict__ Wo,
    const float* __restrict__ bf_, const float* __restrict__ bi_,
    const float* __restrict__ bg_, const float* __restrict__ bo_,
    const float* __restrict__ thf, const float* __restrict__ thi,
    const float* __restrict__ thg, const float* __restrict__ tho,
    unsigned short* __restrict__ Wfull, float* __restrict__ cvec,
    int* __restrict__ flags)
{
  int j = blockIdx.x;            // 0..1023 output col
  int g = j >> 8, col = j & 255;
  const float* W  = (g==0)?Wf:(g==1)?Wi:(g==2)?Wg:Wo;
  const float* bb = (g==0)?bf_:(g==1)?bi_:(g==2)?bg_:bo_;
  const float* th = (g==0)?thf:(g==1)?thi:(g==2)?thg:tho;
  const float* wrow = W + (size_t)col * 768;
  for (int k = threadIdx.x; k < 768; k += blockDim.x)
    Wfull[(size_t)j * 768 + k] = f2bf(wrow[k]);
  if (threadIdx.x == 0) cvec[j] = bb[col] + th[col];
  if (j == 0 && threadIdx.x < 256) flags[threadIdx.x] = 0;
}

// ---------------- persistent kernel ----------------
// blocks 0..63   : recurrence (rows bid*4 .. bid*4+3)
// blocks 64..255 : xgemm workers producing Zx ring chunks
__global__ __launch_bounds__(512, 2) void persist_kernel(
    const float* __restrict__ X,
    const unsigned short* __restrict__ Wfull,
    const float* __restrict__ cvec,
    float* __restrict__ ring,
    int* __restrict__ done,       // [32]
    int* __restrict__ consumed,   // [1]
    float* __restrict__ out)
{
  __shared__ union {
    struct { float z[4][1032]; unsigned short h[2][4][264]; } rec;
    struct { unsigned short a[128][40]; unsigned short b[128][40]; } gem;
  } sm;

  int bid = blockIdx.x, tid = threadIdx.x;
  int lane = tid & 63, wv = tid >> 6;       // 8 waves
  int l15 = lane & 15, lk = lane >> 4;

  if (bid < NRWG) {
    // ================= recurrence =================
    for (int i = tid; i < 2*4*264; i += 512) ((unsigned short*)sm.rec.h)[i] = 0;
    __syncthreads();

    float creg[4] = {0.f, 0.f, 0.f, 0.f};   // c state: col = s*64+lane (wave=row)
    float zx[16];
    int cur = 0;
    int tile0 = wv * 8;                      // 8 col-tiles per wave

    for (int t = 0; t < T_STEPS; ++t) {
      int cIdx = t >> 4;
      if ((t & 15) == 0) {
        if (tid == 0) { while (ld_acq(&done[cIdx]) < TPC) __builtin_amdgcn_s_sleep(2); }
        __syncthreads();
      }
      const float* slot = ring + (size_t)(cIdx & (RING-1)) * SLOT_F;

      // zx prefetch (waves 0..3; row = wv)
      if (wv < 4) {
        const float* zp = slot + ((size_t)(t & 15) * 256 + bid*4 + wv) * 1024 + lane;
#pragma unroll
        for (int c16 = 0; c16 < 16; ++c16) zx[c16] = ldg_coh(zp + c16*64);
      }

      // ---- MFMA: z_h = Wh(cols) x h(batch), D[col][batch] ----
      short8 bfr[8];
      {
        const unsigned short* hb = sm.rec.h[cur][l15 & 3];
#pragma unroll
        for (int kk = 0; kk < 8; ++kk) bfr[kk] = *(const short8*)&hb[kk*32 + lk*8];
      }
      const unsigned short* wp = Wfull + (size_t)(tile0*16 + l15)*768 + 512 + lk*8;
      short8 aP[8], aQ[8];
#pragma unroll
      for (int kk = 0; kk < 8; ++kk) aP[kk] = *(const short8*)(wp + kk*32);
#pragma unroll
      for (int ti = 0; ti < 8; ++ti) {
        short8* ca = (ti & 1) ? aQ : aP;
        short8* na = (ti & 1) ? aP : aQ;
        if (ti < 7) {
          const unsigned short* wpn = wp + (size_t)(ti+1)*16*768;
#pragma unroll
          for (int kk = 0; kk < 8; ++kk) na[kk] = *(const short8*)(wpn + kk*32);
        }
        f32x4 acc = {0.f, 0.f, 0.f, 0.f};
#pragma unroll
        for (int kk = 0; kk < 8; ++kk)
          acc = __builtin_amdgcn_mfma_f32_16x16x32_bf16(ca[kk], bfr[kk], acc, 0, 0, 0);
        if (l15 < 4)   // batch rows 0..3 real; cols (tile0+ti)*16 + lk*4 .. +3
          *(f32x4*)&sm.rec.z[l15][(tile0 + ti)*16 + lk*4] = acc;
      }
      __syncthreads();

      // ---- scan + activation + state update (waves 0..3, wave = row) ----
      if (wv < 4) {
        int r = wv;
        float ag[4][4];
#pragma unroll
        for (int g = 0; g < 4; ++g) {
          float carry = 1.0f;
#pragma unroll
          for (int s = 0; s < 4; ++s) {
            int c16 = g*4 + s;
            float z = sm.rec.z[r][c16*64 + lane] + zx[c16];
            float v = __cosf(z);
#pragma unroll
            for (int off = 1; off < 64; off <<= 1) {
              float u = __shfl_up(v, (unsigned)off, 64);
              if (lane >= off) v *= u;
            }
            v *= carry;
            carry = __shfl(v, 63, 64);
            ag[g][s] = (g == 2) ? tanh_f(v) : sigm(v);
          }
        }
        int brow = bid*4 + r;
        float* op = out + (size_t)t*(BATCH*HID) + (size_t)brow*256 + lane;
#pragma unroll
        for (int s = 0; s < 4; ++s) {
          float cn = ag[0][s]*creg[s] + ag[1][s]*ag[2][s];
          creg[s] = cn;
          float h = ag[3][s]*tanh_f(cn);
          op[s*64] = h;
          sm.rec.h[cur ^ 1][r][s*64 + lane] = f2bf(h);
          if (t == T_STEPS-1) {
            out[(size_t)T_STEPS*(BATCH*HID) + (size_t)brow*256 + s*64 + lane] = h;
            out[(size_t)T_STEPS*(BATCH*HID) + BATCH*HID + (size_t)brow*256 + s*64 + lane] = cn;
          }
        }
      }
      cur ^= 1;
      __syncthreads();
      if ((t & 15) == 15 && tid == 0) add_rel(consumed, 1);
    }
  } else {
    // ================= xgemm workers =================
    int w0 = bid - NRWG;
    int wr = wv >> 2, wc = wv & 3;          // 2 x 4 wave grid, 64x32 per wave
    int r = tid >> 2, k8 = (tid & 3) * 8;   // staging coords

    for (int gt = w0; gt < NCHUNK * TPC; gt += NWWG) {
      int c  = gt >> 8;
      int tl = gt & 255;
      int tm = tl >> 3, tn = tl & 7;

      int need = 64 * (c - RING + 1);
      if (need > 0) {
        if (tid == 0) { while (ld_acq(consumed) < need) __builtin_amdgcn_s_sleep(8); }
        __syncthreads();
      }

      const float* Xb = X + ((size_t)c*4096 + (size_t)tm*128) * 512;
      float* slotp = ring + (size_t)(c & (RING-1)) * SLOT_F;

      f32x4 acc[4][2];
#pragma unroll
      for (int mi = 0; mi < 4; ++mi)
#pragma unroll
        for (int ni = 0; ni < 2; ++ni) acc[mi][ni] = (f32x4){0.f,0.f,0.f,0.f};

      for (int kb = 0; kb < 512; kb += 32) {
        // stage A: X fp32 -> bf16
        const float* ap = Xb + (size_t)r*512 + kb + k8;
        f32x4 v0 = *(const f32x4*)ap;
        f32x4 v1 = *(const f32x4*)(ap + 4);
        unsigned short t8[8];
        t8[0]=f2bf(v0[0]); t8[1]=f2bf(v0[1]); t8[2]=f2bf(v0[2]); t8[3]=f2bf(v0[3]);
        t8[4]=f2bf(v1[0]); t8[5]=f2bf(v1[1]); t8[6]=f2bf(v1[2]); t8[7]=f2bf(v1[3]);
        *(short8*)&sm.gem.a[r][k8] = *(short8*)t8;
        // stage B: Wfull bf16
        const unsigned short* bp = Wfull + (size_t)(tn*128 + r)*768 + kb + k8;
        *(short8*)&sm.gem.b[r][k8] = *(const short8*)bp;
        __syncthreads();

        short8 af[4], bf2[2];
#pragma unroll
        for (int mi = 0; mi < 4; ++mi) af[mi]  = *(const short8*)&sm.gem.a[wr*64 + mi*16 + l15][lk*8];
#pragma unroll
        for (int ni = 0; ni < 2; ++ni) bf2[ni] = *(const short8*)&sm.gem.b[wc*32 + ni*16 + l15][lk*8];
#pragma unroll
        for (int mi = 0; mi < 4; ++mi)
#pragma unroll
          for (int ni = 0; ni < 2; ++ni)
            acc[mi][ni] = __builtin_amdgcn_mfma_f32_16x16x32_bf16(af[mi], bf2[ni], acc[mi][ni], 0, 0, 0);
        __syncthreads();
      }

      // epilogue: + cvec, coherent stores to ring slot
#pragma unroll
      for (int mi = 0; mi < 4; ++mi) {
#pragma unroll
        for (int ni = 0; ni < 2; ++ni) {
          int col = tn*128 + wc*32 + ni*16 + l15;
          float cv = cvec[col];
#pragma unroll
          for (int reg = 0; reg < 4; ++reg) {
            int row = tm*128 + wr*64 + mi*16 + lk*4 + reg;
            stg_coh(&slotp[(size_t)row*1024 + col], acc[mi][ni][reg] + cv);
          }
        }
      }
      __syncthreads();                       // drain all waves' stores
      if (tid == 0) add_rel(&done[c], 1);
    }
  }
}

// ---------------- host ----------------
extern "C" void kernel_launch(void* const* d_in, const int* in_sizes, int n_in,
                              void* d_out, int out_size, void* d_ws, size_t ws_size,
                              hipStream_t stream) {
  const float* x   = (const float*)d_in[0];
  const float* Wf  = (const float*)d_in[1];
  const float* bf_ = (const float*)d_in[2];
  const float* thf = (const float*)d_in[3];
  const float* Wi  = (const float*)d_in[4];
  const float* bi_ = (const float*)d_in[5];
  const float* thi = (const float*)d_in[6];
  const float* Wg  = (const float*)d_in[7];
  const float* bg_ = (const float*)d_in[8];
  const float* thg = (const float*)d_in[9];
  const float* Wo  = (const float*)d_in[10];
  const float* bo_ = (const float*)d_in[11];
  const float* tho = (const float*)d_in[12];
  float* out = (float*)d_out;

  char* ws = (char*)d_ws;
  unsigned short* Wfull = (unsigned short*)ws;            // 1,572,864 B
  float* cvec = (float*)(ws + 1572864);                   // 4 KB
  int*   flags = (int*)(ws + 1576960);                    // done[32] @0, consumed @128
  float* ring = (float*)(ws + 2097152);                   // RING x 16 MB

  prep_kernel<<<1024, 256, 0, stream>>>(Wf, Wi, Wg, Wo, bf_, bi_, bg_, bo_,
                                        thf, thi, thg, tho, Wfull, cvec, flags);
  persist_kernel<<<NWG, 512, 0, stream>>>(x, Wfull, cvec, ring,
                                          flags, flags + 128, out);
}

// Round 3
// 4693.266 us; speedup vs baseline: 2.2970x; 2.2970x over previous
//
#include <hip/hip_runtime.h>
#include <hip/hip_bf16.h>
#include <stdint.h>

#define T_STEPS 512
#define BATCH   256
#define HID     256

#define NRWG   128     // recurrence WGs: 32 batch-groups x 4 gates
#define NWWG   128     // xgemm producer WGs
#define NWG    256
#define RING   4       // ring slots
#define CHUNK  8       // time steps per chunk
#define NCHUNK 64
#define TPC    128     // tiles per chunk: (8*256/128) * (1024/128)
#define SLOT_F (CHUNK*256*1024)   // floats per ring slot (8 MB)

using short8 = __attribute__((ext_vector_type(8))) short;
using f32x4  = __attribute__((ext_vector_type(4))) float;

__device__ inline unsigned short f2bf(float f) {
  unsigned u = __float_as_uint(f);
  unsigned r = (u + 0x7fffu + ((u >> 16) & 1u)) >> 16;
  return (unsigned short)r;
}
__device__ inline float sigm(float x)   { return __builtin_amdgcn_rcpf(1.0f + __expf(-x)); }
__device__ inline float tanh_f(float x) { return 2.0f * __builtin_amdgcn_rcpf(1.0f + __expf(-2.0f * x)) - 1.0f; }

__device__ inline int ld_acq(const int* p) {
  return __hip_atomic_load(p, __ATOMIC_ACQUIRE, __HIP_MEMORY_SCOPE_AGENT);
}
__device__ inline void st_rel(int* p, int v) {
  __hip_atomic_store(p, v, __ATOMIC_RELEASE, __HIP_MEMORY_SCOPE_AGENT);
}
__device__ inline void add_rel(int* p, int v) {
  __hip_atomic_fetch_add(p, v, __ATOMIC_RELEASE, __HIP_MEMORY_SCOPE_AGENT);
}
__device__ inline float ldg_coh(const float* p) {
  return __hip_atomic_load(p, __ATOMIC_RELAXED, __HIP_MEMORY_SCOPE_AGENT);
}
__device__ inline void stg_coh(float* p, float v) {
  __hip_atomic_store(p, v, __ATOMIC_RELAXED, __HIP_MEMORY_SCOPE_AGENT);
}

// ---------------- prep: pack weights + zero flags ----------------
// Wfull : [1024 cols][768 k] bf16 (k 0..511 = x part, 512..767 = h part)
// cvec  : [1024] = bias + theta
__global__ __launch_bounds__(256) void prep_kernel(
    const float* __restrict__ Wf, const float* __restrict__ Wi,
    const float* __restrict__ Wg, const float* __restrict__ Wo,
    const float* __restrict__ bf_, const float* __restrict__ bi_,
    const float* __restrict__ bg_, const float* __restrict__ bo_,
    const float* __restrict__ thf, const float* __restrict__ thi,
    const float* __restrict__ thg, const float* __restrict__ tho,
    unsigned short* __restrict__ Wfull, float* __restrict__ cvec,
    int* __restrict__ flags)
{
  int j = blockIdx.x;            // 0..1023 output col
  int g = j >> 8, col = j & 255;
  const float* W  = (g==0)?Wf:(g==1)?Wi:(g==2)?Wg:Wo;
  const float* bb = (g==0)?bf_:(g==1)?bi_:(g==2)?bg_:bo_;
  const float* th = (g==0)?thf:(g==1)?thi:(g==2)?thg:tho;
  const float* wrow = W + (size_t)col * 768;
  for (int k = threadIdx.x; k < 768; k += blockDim.x)
    Wfull[(size_t)j * 768 + k] = f2bf(wrow[k]);
  if (threadIdx.x == 0) cvec[j] = bb[col] + th[col];
  if (j == 0) for (int i = threadIdx.x; i < 512; i += 256) flags[i] = 0;
}

// ---------------- persistent kernel ----------------
// blocks 0..127   : recurrence, (bg = bid>>2) batch rows bg*8..+7, gate = bid&3
// blocks 128..255 : xgemm producers filling the Zx ring
__global__ __launch_bounds__(512, 2) void persist_kernel(
    const float* __restrict__ X,
    const unsigned short* __restrict__ Wfull,
    const float* __restrict__ cvec,
    float* __restrict__ ring,
    float* __restrict__ exch,     // [2][32][4][8][256] fp32
    int* __restrict__ done,       // [64]
    int* __restrict__ consumed,   // [1]
    int* __restrict__ seq,        // [2][128]
    float* __restrict__ out)
{
  __shared__ union {
    struct { unsigned short h[16][264]; float z[8][264]; } rec;
    struct { unsigned short a[128][40]; unsigned short b[128][40]; } gem;
  } sm;

  int bid = blockIdx.x, tid = threadIdx.x;
  int lane = tid & 63, wv = tid >> 6;       // 8 waves
  int l15 = lane & 15, lk = lane >> 4;

  if (bid < NRWG) {
    // ================= recurrence =================
    int bg = bid >> 2, g = bid & 3;

    // zero h buffer (rows 8..15 stay zero forever)
    for (int i = tid; i < 16*264; i += 512) ((unsigned short*)sm.rec.h)[i] = 0;

    // Wh fragments -> registers (one-time). wave wv covers gate cols wv*32..+31
    short8 af[2][8];
#pragma unroll
    for (int ti = 0; ti < 2; ++ti)
#pragma unroll
      for (int kk = 0; kk < 8; ++kk)
        af[ti][kk] = *(const short8*)(Wfull +
            (size_t)(g*256 + wv*32 + ti*16 + l15)*768 + 512 + kk*32 + lk*8);

    float creg[4] = {0.f, 0.f, 0.f, 0.f};   // c-state: row=wv, col=s*64+lane
    float zx[4];
    __syncthreads();

    for (int t = 0; t < T_STEPS; ++t) {
      int cIdx = t >> 3;
      if ((t & 7) == 0) {
        if (tid == 0) { while (ld_acq(&done[cIdx]) < TPC) __builtin_amdgcn_s_sleep(1); }
        __syncthreads();
        const float* zp = ring + (size_t)(cIdx & (RING-1))*SLOT_F
                        + ((size_t)(t & 7)*256 + bg*8 + wv)*1024 + g*256 + lane;
#pragma unroll
        for (int s = 0; s < 4; ++s) zx[s] = ldg_coh(zp + s*64);
      }

      // ---- MFMA: z_h = Wh_cols x h_rows ----
      short8 bfr[8];
#pragma unroll
      for (int kk = 0; kk < 8; ++kk)
        bfr[kk] = *(const short8*)&sm.rec.h[l15][kk*32 + lk*8];
      f32x4 acc0 = {0.f,0.f,0.f,0.f}, acc1 = {0.f,0.f,0.f,0.f};
#pragma unroll
      for (int kk = 0; kk < 8; ++kk) {
        acc0 = __builtin_amdgcn_mfma_f32_16x16x32_bf16(af[0][kk], bfr[kk], acc0, 0, 0, 0);
        acc1 = __builtin_amdgcn_mfma_f32_16x16x32_bf16(af[1][kk], bfr[kk], acc1, 0, 0, 0);
      }
      if (l15 < 8) {   // D: col(batch)=l15, row(Wh col)=lk*4+reg
        *(f32x4*)&sm.rec.z[l15][wv*32 +      lk*4] = acc0;
        *(f32x4*)&sm.rec.z[l15][wv*32 + 16 + lk*4] = acc1;
      }
      __syncthreads();

      // ---- scan + activation (wave wv = batch row) ----
      float v[4];
#pragma unroll
      for (int s = 0; s < 4; ++s)
        v[s] = __cosf(sm.rec.z[wv][s*64 + lane] + zx[s]);
#pragma unroll
      for (int off = 1; off < 64; off <<= 1) {
        float u0 = __shfl_up(v[0], (unsigned)off, 64);
        float u1 = __shfl_up(v[1], (unsigned)off, 64);
        float u2 = __shfl_up(v[2], (unsigned)off, 64);
        float u3 = __shfl_up(v[3], (unsigned)off, 64);
        if (lane >= off) { v[0]*=u0; v[1]*=u1; v[2]*=u2; v[3]*=u3; }
      }
      float t0 = __shfl(v[0], 63, 64), t1 = __shfl(v[1], 63, 64), t2 = __shfl(v[2], 63, 64);
      float p1 = t0, p2 = t0*t1, p3 = p2*t2;
      float a0 = v[0], a1 = v[1]*p1, a2 = v[2]*p2, a3 = v[3]*p3;
      float act[4];
      if (g == 2) { act[0]=tanh_f(a0); act[1]=tanh_f(a1); act[2]=tanh_f(a2); act[3]=tanh_f(a3); }
      else        { act[0]=sigm(a0);   act[1]=sigm(a1);   act[2]=sigm(a2);   act[3]=sigm(a3); }

      int par = t & 1;
      float* exw = exch + (((size_t)par*32 + bg)*4 + g)*2048 + wv*256 + lane;
#pragma unroll
      for (int s = 0; s < 4; ++s) stg_coh(exw + s*64, act[s]);

      // prefetch zx for t+1 (hidden under exchange latency)
      if (((t+1) & 7) != 0 && t+1 < T_STEPS) {
        const float* zp = ring + (size_t)(((t+1) >> 3) & (RING-1))*SLOT_F
                        + ((size_t)((t+1) & 7)*256 + bg*8 + wv)*1024 + g*256 + lane;
#pragma unroll
        for (int s = 0; s < 4; ++s) zx[s] = ldg_coh(zp + s*64);
      }

      __syncthreads();   // drains vmcnt: act stores + zx loads complete
      if (tid == 0) st_rel(&seq[par*128 + bid], t + 1);
      if (tid < 3) {
        int og = (g + 1 + tid) & 3;
        while (ld_acq(&seq[par*128 + bg*4 + og]) < t + 1) {}
      }
      __syncthreads();

      // ---- load all 4 gates, update c,h ----
      const float* exb = exch + ((size_t)par*32 + bg)*4*2048 + wv*256 + lane;
      float vals[4][4];
#pragma unroll
      for (int q = 0; q < 4; ++q)
#pragma unroll
        for (int s = 0; s < 4; ++s)
          vals[q][s] = ldg_coh(exb + q*2048 + s*64);

      int brow = bg*8 + wv;
#pragma unroll
      for (int s = 0; s < 4; ++s) {
        float cn = vals[0][s]*creg[s] + vals[1][s]*vals[2][s];
        creg[s] = cn;
        float h = vals[3][s]*tanh_f(cn);
        sm.rec.h[wv][s*64 + lane] = f2bf(h);
        if (g == 0) {
          out[(size_t)t*(BATCH*HID) + (size_t)brow*256 + s*64 + lane] = h;
          if (t == T_STEPS-1) {
            out[(size_t)T_STEPS*(BATCH*HID) + (size_t)brow*256 + s*64 + lane] = h;
            out[(size_t)T_STEPS*(BATCH*HID) + BATCH*HID + (size_t)brow*256 + s*64 + lane] = cn;
          }
        }
      }
      if ((t & 7) == 7 && tid == 0) add_rel(consumed, 1);
      __syncthreads();   // h ready for next step's MFMA
    }
  } else {
    // ================= xgemm producers =================
    int w0 = bid - NRWG;
    int wr = wv >> 2, wc = wv & 3;          // 2 x 4 wave grid, 64x32 per wave
    int r = tid >> 2, k8 = (tid & 3) * 8;   // staging coords

    for (int gt = w0; gt < NCHUNK * TPC; gt += NWWG) {
      int c  = gt >> 7;
      int tl = gt & 127;
      int tm = tl >> 3, tn = tl & 7;

      int need = NRWG * (c - RING + 1);
      if (need > 0) {
        if (tid == 0) { while (ld_acq(consumed) < need) __builtin_amdgcn_s_sleep(8); }
        __syncthreads();
      }

      const float* Xb = X + ((size_t)c*(CHUNK*256) + (size_t)tm*128) * 512;
      float* slotp = ring + (size_t)(c & (RING-1)) * SLOT_F;

      f32x4 acc[4][2];
#pragma unroll
      for (int mi = 0; mi < 4; ++mi)
#pragma unroll
        for (int ni = 0; ni < 2; ++ni) acc[mi][ni] = (f32x4){0.f,0.f,0.f,0.f};

      for (int kb = 0; kb < 512; kb += 32) {
        const float* ap = Xb + (size_t)r*512 + kb + k8;
        f32x4 v0 = *(const f32x4*)ap;
        f32x4 v1 = *(const f32x4*)(ap + 4);
        unsigned short t8[8];
        t8[0]=f2bf(v0[0]); t8[1]=f2bf(v0[1]); t8[2]=f2bf(v0[2]); t8[3]=f2bf(v0[3]);
        t8[4]=f2bf(v1[0]); t8[5]=f2bf(v1[1]); t8[6]=f2bf(v1[2]); t8[7]=f2bf(v1[3]);
        *(short8*)&sm.gem.a[r][k8] = *(short8*)t8;
        const unsigned short* bp = Wfull + (size_t)(tn*128 + r)*768 + kb + k8;
        *(short8*)&sm.gem.b[r][k8] = *(const short8*)bp;
        __syncthreads();

        short8 afr[4], bf2[2];
#pragma unroll
        for (int mi = 0; mi < 4; ++mi) afr[mi] = *(const short8*)&sm.gem.a[wr*64 + mi*16 + l15][lk*8];
#pragma unroll
        for (int ni = 0; ni < 2; ++ni) bf2[ni] = *(const short8*)&sm.gem.b[wc*32 + ni*16 + l15][lk*8];
#pragma unroll
        for (int mi = 0; mi < 4; ++mi)
#pragma unroll
          for (int ni = 0; ni < 2; ++ni)
            acc[mi][ni] = __builtin_amdgcn_mfma_f32_16x16x32_bf16(afr[mi], bf2[ni], acc[mi][ni], 0, 0, 0);
        __syncthreads();
      }

#pragma unroll
      for (int mi = 0; mi < 4; ++mi) {
#pragma unroll
        for (int ni = 0; ni < 2; ++ni) {
          int col = tn*128 + wc*32 + ni*16 + l15;
          float cv = cvec[col];
#pragma unroll
          for (int reg = 0; reg < 4; ++reg) {
            int row = tm*128 + wr*64 + mi*16 + lk*4 + reg;
            stg_coh(&slotp[(size_t)row*1024 + col], acc[mi][ni][reg] + cv);
          }
        }
      }
      __syncthreads();                       // drain all waves' stores
      if (tid == 0) add_rel(&done[c], 1);
    }
  }
}

// ---------------- host ----------------
extern "C" void kernel_launch(void* const* d_in, const int* in_sizes, int n_in,
                              void* d_out, int out_size, void* d_ws, size_t ws_size,
                              hipStream_t stream) {
  const float* x   = (const float*)d_in[0];
  const float* Wf  = (const float*)d_in[1];
  const float* bf_ = (const float*)d_in[2];
  const float* thf = (const float*)d_in[3];
  const float* Wi  = (const float*)d_in[4];
  const float* bi_ = (const float*)d_in[5];
  const float* thi = (const float*)d_in[6];
  const float* Wg  = (const float*)d_in[7];
  const float* bg_ = (const float*)d_in[8];
  const float* thg = (const float*)d_in[9];
  const float* Wo  = (const float*)d_in[10];
  const float* bo_ = (const float*)d_in[11];
  const float* tho = (const float*)d_in[12];
  float* out = (float*)d_out;

  char* ws = (char*)d_ws;
  unsigned short* Wfull = (unsigned short*)ws;            // 1.5 MB
  float* cvec  = (float*)(ws + 1572864);                  // 4 KB
  int*   flags = (int*)(ws + 1576960);                    // 512 ints
  float* exch  = (float*)(ws + 2097152);                  // 2 MB
  float* ring  = (float*)(ws + 4194304);                  // RING x 8 MB = 32 MB

  prep_kernel<<<1024, 256, 0, stream>>>(Wf, Wi, Wg, Wo, bf_, bi_, bg_, bo_,
                                        thf, thi, thg, tho, Wfull, cvec, flags);
  persist_kernel<<<NWG, 512, 0, stream>>>(x, Wfull, cvec, ring, exch,
                                          flags, flags + 128, flags + 256, out);
}

// Round 4
// 2208.971 us; speedup vs baseline: 4.8804x; 2.1246x over previous
//
#include <hip/hip_runtime.h>
#include <hip/hip_bf16.h>
#include <stdint.h>

#define T_STEPS 512
#define BATCH   256
#define HID     256

#define NRWG   128     // recurrence WGs: 32 batch-groups x 4 gates
#define NWWG   128     // xgemm producer WGs
#define NWG    256
#define RING   4       // ring slots
#define CHUNK  8       // time steps per chunk
#define NCHUNK 64
#define TPC    64      // tiles per chunk: (8*256/128) * (1024/256)
#define SLOT_F (CHUNK*256*1024)   // floats per ring slot (8 MB)

using short8 = __attribute__((ext_vector_type(8))) short;
using f32x4  = __attribute__((ext_vector_type(4))) float;

#define VMCNT0() asm volatile("s_waitcnt vmcnt(0)" ::: "memory")

__device__ inline unsigned short f2bf(float f) {
  unsigned u = __float_as_uint(f);
  unsigned r = (u + 0x7fffu + ((u >> 16) & 1u)) >> 16;
  return (unsigned short)r;
}
__device__ inline float sigm(float x)   { return __builtin_amdgcn_rcpf(1.0f + __expf(-x)); }
__device__ inline float tanh_f(float x) { return 2.0f * __builtin_amdgcn_rcpf(1.0f + __expf(-2.0f * x)) - 1.0f; }

// ALL cross-WG traffic: relaxed agent-scope atomics (sc1 -> coherent LLC,
// bypassing the non-coherent per-XCD L2). No acquire/release: those emit
// buffer_inv / buffer_wbl2 (whole-L2 maintenance) on gfx950 — the round-3
// killer. Ordering is done with explicit s_waitcnt vmcnt(0) + barriers.
__device__ inline int ld_rlx(const int* p) {
  return __hip_atomic_load(p, __ATOMIC_RELAXED, __HIP_MEMORY_SCOPE_AGENT);
}
__device__ inline void st_rlx(int* p, int v) {
  __hip_atomic_store(p, v, __ATOMIC_RELAXED, __HIP_MEMORY_SCOPE_AGENT);
}
__device__ inline void add_rlx(int* p, int v) {
  __hip_atomic_fetch_add(p, v, __ATOMIC_RELAXED, __HIP_MEMORY_SCOPE_AGENT);
}
__device__ inline float ldg_coh(const float* p) {
  return __hip_atomic_load(p, __ATOMIC_RELAXED, __HIP_MEMORY_SCOPE_AGENT);
}
__device__ inline void stg_coh(float* p, float v) {
  __hip_atomic_store(p, v, __ATOMIC_RELAXED, __HIP_MEMORY_SCOPE_AGENT);
}

// ---------------- prep: pack weights + zero flags ----------------
// Wfull : [1024 cols][768 k] bf16 (k 0..511 = x part, 512..767 = h part)
// cvec  : [1024] = bias + theta
__global__ __launch_bounds__(256) void prep_kernel(
    const float* __restrict__ Wf, const float* __restrict__ Wi,
    const float* __restrict__ Wg, const float* __restrict__ Wo,
    const float* __restrict__ bf_, const float* __restrict__ bi_,
    const float* __restrict__ bg_, const float* __restrict__ bo_,
    const float* __restrict__ thf, const float* __restrict__ thi,
    const float* __restrict__ thg, const float* __restrict__ tho,
    unsigned short* __restrict__ Wfull, float* __restrict__ cvec,
    int* __restrict__ flags)
{
  int j = blockIdx.x;            // 0..1023 output col
  int g = j >> 8, col = j & 255;
  const float* W  = (g==0)?Wf:(g==1)?Wi:(g==2)?Wg:Wo;
  const float* bb = (g==0)?bf_:(g==1)?bi_:(g==2)?bg_:bo_;
  const float* th = (g==0)?thf:(g==1)?thi:(g==2)?thg:tho;
  const float* wrow = W + (size_t)col * 768;
  for (int k = threadIdx.x; k < 768; k += blockDim.x)
    Wfull[(size_t)j * 768 + k] = f2bf(wrow[k]);
  if (threadIdx.x == 0) cvec[j] = bb[col] + th[col];
  if (j == 0) for (int i = threadIdx.x; i < 512; i += 256) flags[i] = 0;
}

// ---------------- persistent kernel ----------------
// blocks 0..127   : recurrence, bg = bid>>2 (batch rows bg*8..+7), gate = bid&3
// blocks 128..255 : xgemm producers filling the Zx ring
__global__ __launch_bounds__(512, 2) void persist_kernel(
    const float* __restrict__ X,
    const unsigned short* __restrict__ Wfull,
    const float* __restrict__ cvec,
    float* __restrict__ ring,
    float* __restrict__ exch,     // [2][32][4][8][256] fp32
    int* __restrict__ done,       // [64]
    int* __restrict__ consumed,   // [1]
    int* __restrict__ seq,        // [2][128]
    float* __restrict__ out)
{
  __shared__ union {
    struct { unsigned short h[16][264]; float z[8][264]; } rec;
    struct { unsigned short a[128][40]; unsigned short b[256][40]; } gem;
  } sm;

  int bid = blockIdx.x, tid = threadIdx.x;
  int lane = tid & 63, wv = tid >> 6;       // 8 waves
  int l15 = lane & 15, lk = lane >> 4;

  if (bid < NRWG) {
    // ================= recurrence =================
    int bg = bid >> 2, g = bid & 3;

    for (int i = tid; i < 16*264; i += 512) ((unsigned short*)sm.rec.h)[i] = 0;

    // Wh fragments (wave wv covers gate cols wv*32..+31)
    short8 af[2][8];
#pragma unroll
    for (int ti = 0; ti < 2; ++ti)
#pragma unroll
      for (int kk = 0; kk < 8; ++kk)
        af[ti][kk] = *(const short8*)(Wfull +
            (size_t)(g*256 + wv*32 + ti*16 + l15)*768 + 512 + kk*32 + lk*8);

    float creg[4] = {0.f, 0.f, 0.f, 0.f};   // c-state: row=wv, col=s*64+lane
    float zx[4];
    __syncthreads();

    for (int t = 0; t < T_STEPS; ++t) {
      int cIdx = t >> 3;
      if ((t & 7) == 0) {
        if (tid == 0) { while (ld_rlx(&done[cIdx]) < TPC) __builtin_amdgcn_s_sleep(1); }
        __syncthreads();
        const float* zp = ring + (size_t)(cIdx & (RING-1))*SLOT_F
                        + ((size_t)(t & 7)*256 + bg*8 + wv)*1024 + g*256 + lane;
#pragma unroll
        for (int s = 0; s < 4; ++s) zx[s] = ldg_coh(zp + s*64);
      }

      // ---- MFMA: z_h = Wh_cols x h_rows ----
      short8 bfr[8];
#pragma unroll
      for (int kk = 0; kk < 8; ++kk)
        bfr[kk] = *(const short8*)&sm.rec.h[l15][kk*32 + lk*8];
      f32x4 acc0 = {0.f,0.f,0.f,0.f}, acc1 = {0.f,0.f,0.f,0.f};
#pragma unroll
      for (int kk = 0; kk < 8; ++kk) {
        acc0 = __builtin_amdgcn_mfma_f32_16x16x32_bf16(af[0][kk], bfr[kk], acc0, 0, 0, 0);
        acc1 = __builtin_amdgcn_mfma_f32_16x16x32_bf16(af[1][kk], bfr[kk], acc1, 0, 0, 0);
      }
      if (l15 < 8) {   // D: col(batch)=l15, row(Wh col)=lk*4+reg
        *(f32x4*)&sm.rec.z[l15][wv*32 +      lk*4] = acc0;
        *(f32x4*)&sm.rec.z[l15][wv*32 + 16 + lk*4] = acc1;
      }
      __syncthreads();

      // ---- scan + activation (wave wv = batch row) ----
      float v[4];
#pragma unroll
      for (int s = 0; s < 4; ++s)
        v[s] = __cosf(sm.rec.z[wv][s*64 + lane] + zx[s]);
#pragma unroll
      for (int off = 1; off < 64; off <<= 1) {
        float u0 = __shfl_up(v[0], (unsigned)off, 64);
        float u1 = __shfl_up(v[1], (unsigned)off, 64);
        float u2 = __shfl_up(v[2], (unsigned)off, 64);
        float u3 = __shfl_up(v[3], (unsigned)off, 64);
        if (lane >= off) { v[0]*=u0; v[1]*=u1; v[2]*=u2; v[3]*=u3; }
      }
      float t0 = __shfl(v[0], 63, 64), t1 = __shfl(v[1], 63, 64), t2 = __shfl(v[2], 63, 64);
      float p1 = t0, p2 = t0*t1, p3 = p2*t2;
      float a0 = v[0], a1 = v[1]*p1, a2 = v[2]*p2, a3 = v[3]*p3;
      float act[4];
      if (g == 2) { act[0]=tanh_f(a0); act[1]=tanh_f(a1); act[2]=tanh_f(a2); act[3]=tanh_f(a3); }
      else        { act[0]=sigm(a0);   act[1]=sigm(a1);   act[2]=sigm(a2);   act[3]=sigm(a3); }

      // ---- publish acts: data stores -> per-wave vmcnt drain -> barrier -> flag
      int par = t & 1;
      float* exw = exch + (((size_t)par*32 + bg)*4 + g)*2048 + wv*256 + lane;
#pragma unroll
      for (int s = 0; s < 4; ++s) stg_coh(exw + s*64, act[s]);
      VMCNT0();
      __syncthreads();
      if (tid == 0) st_rlx(&seq[par*128 + bid], t + 1);

      // zx prefetch for t+1 (overlaps the poll below)
      if (((t+1) & 7) != 0 && t+1 < T_STEPS) {
        const float* zp = ring + (size_t)(((t+1) >> 3) & (RING-1))*SLOT_F
                        + ((size_t)((t+1) & 7)*256 + bg*8 + wv)*1024 + g*256 + lane;
#pragma unroll
        for (int s = 0; s < 4; ++s) zx[s] = ldg_coh(zp + s*64);
      }

      // ---- per-wave poll of the 3 peer gates (relaxed; no cache maintenance)
      if (lane < 3) {
        int og = (g + 1 + lane) & 3;
        const int* fp = &seq[par*128 + bg*4 + og];
        while (ld_rlx(fp) < t + 1) { }
      }
      asm volatile("" ::: "memory");

      // ---- load peer acts (own gate from registers), update c,h ----
      const float* exb = exch + ((size_t)par*32 + bg)*4*2048 + wv*256 + lane;
      float vals[4][4];
#pragma unroll
      for (int q = 0; q < 4; ++q) {
        if (q == g) {
#pragma unroll
          for (int s = 0; s < 4; ++s) vals[q][s] = act[s];
        } else {
#pragma unroll
          for (int s = 0; s < 4; ++s) vals[q][s] = ldg_coh(exb + q*2048 + s*64);
        }
      }

      int brow = bg*8 + wv;
#pragma unroll
      for (int s = 0; s < 4; ++s) {
        float cn = vals[0][s]*creg[s] + vals[1][s]*vals[2][s];
        creg[s] = cn;
        float h = vals[3][s]*tanh_f(cn);
        sm.rec.h[wv][s*64 + lane] = f2bf(h);
        if (g == 0) {
          out[(size_t)t*(BATCH*HID) + (size_t)brow*256 + s*64 + lane] = h;
          if (t == T_STEPS-1) {
            out[(size_t)T_STEPS*(BATCH*HID) + (size_t)brow*256 + s*64 + lane] = h;
            out[(size_t)T_STEPS*(BATCH*HID) + BATCH*HID + (size_t)brow*256 + s*64 + lane] = cn;
          }
        }
      }
      if ((t & 7) == 7 && tid == 0) add_rlx(consumed, 1);
      __syncthreads();   // h ready for next step's MFMA
    }
  } else {
    // ================= xgemm producers (128x256 tiles) =================
    int w0 = bid - NRWG;
    int wr = wv >> 2, wc = wv & 3;          // 2 x 4 wave grid, 64x64 per wave
    int rA = tid >> 2, kA = (tid & 3) * 8;  // A staging: 128 rows x 32 k
    int rB = tid >> 1, kB = (tid & 1) * 16; // B staging: 256 cols x 32 k

    for (int gt = w0; gt < NCHUNK * TPC; gt += NWWG) {
      int c  = gt >> 6;
      int tl = gt & 63;
      int tm = tl >> 2, tn = tl & 3;

      int need = NRWG * (c - RING + 1);
      if (need > 0) {
        if (tid == 0) { while (ld_rlx(consumed) < need) __builtin_amdgcn_s_sleep(8); }
        __syncthreads();
      }

      const float* Xb = X + ((size_t)c*(CHUNK*256) + (size_t)tm*128) * 512;
      float* slotp = ring + (size_t)(c & (RING-1)) * SLOT_F;

      f32x4 acc[4][4];
#pragma unroll
      for (int mi = 0; mi < 4; ++mi)
#pragma unroll
        for (int ni = 0; ni < 4; ++ni) acc[mi][ni] = (f32x4){0.f,0.f,0.f,0.f};

      for (int kb = 0; kb < 512; kb += 32) {
        const float* ap = Xb + (size_t)rA*512 + kb + kA;
        f32x4 v0 = *(const f32x4*)ap;
        f32x4 v1 = *(const f32x4*)(ap + 4);
        unsigned short t8[8];
        t8[0]=f2bf(v0[0]); t8[1]=f2bf(v0[1]); t8[2]=f2bf(v0[2]); t8[3]=f2bf(v0[3]);
        t8[4]=f2bf(v1[0]); t8[5]=f2bf(v1[1]); t8[6]=f2bf(v1[2]); t8[7]=f2bf(v1[3]);
        *(short8*)&sm.gem.a[rA][kA] = *(short8*)t8;
        const unsigned short* bp = Wfull + (size_t)(tn*256 + rB)*768 + kb + kB;
        *(short8*)&sm.gem.b[rB][kB]     = *(const short8*)bp;
        *(short8*)&sm.gem.b[rB][kB + 8] = *(const short8*)(bp + 8);
        __syncthreads();

        short8 afr[4], bfr4[4];
#pragma unroll
        for (int mi = 0; mi < 4; ++mi) afr[mi]  = *(const short8*)&sm.gem.a[wr*64 + mi*16 + l15][lk*8];
#pragma unroll
        for (int ni = 0; ni < 4; ++ni) bfr4[ni] = *(const short8*)&sm.gem.b[wc*64 + ni*16 + l15][lk*8];
#pragma unroll
        for (int mi = 0; mi < 4; ++mi)
#pragma unroll
          for (int ni = 0; ni < 4; ++ni)
            acc[mi][ni] = __builtin_amdgcn_mfma_f32_16x16x32_bf16(afr[mi], bfr4[ni], acc[mi][ni], 0, 0, 0);
        __syncthreads();
      }

#pragma unroll
      for (int mi = 0; mi < 4; ++mi) {
#pragma unroll
        for (int ni = 0; ni < 4; ++ni) {
          int col = tn*256 + wc*64 + ni*16 + l15;
          float cv = cvec[col];
#pragma unroll
          for (int reg = 0; reg < 4; ++reg) {
            int row = tm*128 + wr*64 + mi*16 + lk*4 + reg;
            stg_coh(&slotp[(size_t)row*1024 + col], acc[mi][ni][reg] + cv);
          }
        }
      }
      VMCNT0();
      __syncthreads();                       // all waves' stores at LLC
      if (tid == 0) add_rlx(&done[c], 1);
    }
  }
}

// ---------------- host ----------------
extern "C" void kernel_launch(void* const* d_in, const int* in_sizes, int n_in,
                              void* d_out, int out_size, void* d_ws, size_t ws_size,
                              hipStream_t stream) {
  const float* x   = (const float*)d_in[0];
  const float* Wf  = (const float*)d_in[1];
  const float* bf_ = (const float*)d_in[2];
  const float* thf = (const float*)d_in[3];
  const float* Wi  = (const float*)d_in[4];
  const float* bi_ = (const float*)d_in[5];
  const float* thi = (const float*)d_in[6];
  const float* Wg  = (const float*)d_in[7];
  const float* bg_ = (const float*)d_in[8];
  const float* thg = (const float*)d_in[9];
  const float* Wo  = (const float*)d_in[10];
  const float* bo_ = (const float*)d_in[11];
  const float* tho = (const float*)d_in[12];
  float* out = (float*)d_out;

  char* ws = (char*)d_ws;
  unsigned short* Wfull = (unsigned short*)ws;            // 1.5 MB
  float* cvec  = (float*)(ws + 1572864);                  // 4 KB
  int*   flags = (int*)(ws + 1576960);                    // 512 ints
  float* exch  = (float*)(ws + 2097152);                  // 2 MB
  float* ring  = (float*)(ws + 4194304);                  // RING x 8 MB = 32 MB

  prep_kernel<<<1024, 256, 0, stream>>>(Wf, Wi, Wg, Wo, bf_, bi_, bg_, bo_,
                                        thf, thi, thg, tho, Wfull, cvec, flags);
  persist_kernel<<<NWG, 512, 0, stream>>>(x, Wfull, cvec, ring, exch,
                                          flags, flags + 128, flags + 256, out);
}